// Round 5
// baseline (1277.953 us; speedup 1.0000x reference)
//
#include <hip/hip_runtime.h>
#include <hip/hip_bf16.h>

#define BT 2048
#define VOC 32000
#define IGN (-100)

typedef __attribute__((ext_vector_type(4))) float f32x4;
typedef __attribute__((ext_vector_type(8))) short s16x8;
typedef __attribute__((ext_vector_type(4))) unsigned int u32x4;

#define AS1 __attribute__((address_space(1)))
#define AS3 __attribute__((address_space(3)))

__device__ __forceinline__ unsigned short f2bf(float f) {
    union { __hip_bfloat16 h; unsigned short u; } c;
    c.h = __float2bfloat16(f);
    return c.u;
}
__device__ __forceinline__ float bf2f(unsigned short u) {
    union { unsigned int u; float f; } c;
    c.u = ((unsigned int)u) << 16;
    return c.f;
}
__device__ __forceinline__ unsigned int pk2(float a, float b) {
    return (unsigned int)f2bf(a) | ((unsigned int)f2bf(b) << 16);
}

// ---------------------------------------------------------------------------
// fp32 -> bf16 pre-convert (memory-bound)
// ---------------------------------------------------------------------------
__global__ __launch_bounds__(256)
void cvt_kernel(const float* __restrict__ in, unsigned short* __restrict__ out, int n8) {
    for (int i = blockIdx.x * 256 + threadIdx.x; i < n8; i += gridDim.x * 256) {
        f32x4 a = ((const f32x4*)in)[2 * i];
        f32x4 b = ((const f32x4*)in)[2 * i + 1];
        u32x4 o;
        o[0] = pk2(a[0], a[1]);
        o[1] = pk2(a[2], a[3]);
        o[2] = pk2(b[0], b[1]);
        o[3] = pk2(b[2], b[3]);
        ((u32x4*)out)[i] = o;
    }
}

// ---------------------------------------------------------------------------
// 256x256 GEMM (bf16 operands), 4-region K-half ring, 1 barrier per phase.
// C[m,v] = sum_k A[m,k] * W[v,k].  BK=64 = 2 K-halves (one 16x16x32 step each).
// 512 thr (8 waves 2Mx4N), per-wave 128x64 out.
//
// vs round 4: NO explicit lgkmcnt(0)/sched_barrier before the MFMA burst —
// the data in region r has been resident for >=2 barriers, so each wave only
// depends on its OWN ds_reads and the compiler emits fine-grained counted
// lgkmcnt per MFMA (Guideline 7).  K-loop unrolled by tile-pairs so the
// region index is compile-time.  Ring/vmcnt(4) discipline unchanged:
// phase p consumes region p%4, stages region (p+2)%4 (dead >=2 barriers),
// vmcnt(4) at phase end guarantees next phase's region landed while keeping
// this phase's 4 gloads in flight.
// ---------------------------------------------------------------------------
#define FENCE() asm volatile("" ::: "memory")
#define BARRIER() do { FENCE(); __builtin_amdgcn_s_barrier(); FENCE(); } while (0)

#define STAGEH(larr, Base, kh, t, r) do { if ((t) < nsteps) {                 \
    _Pragma("unroll")                                                         \
    for (int l_ = 0; l_ < 2; ++l_) {                                          \
        const int gi_ = (wave * 2 + l_) * 64 + lane;                          \
        const int rp_ = gi_ >> 3, sgi_ = gi_ & 7;                             \
        const int raw_ = sgi_ ^ (rp_ & 7);                                    \
        const int row_ = rp_ * 2 + (raw_ >> 2);                               \
        const int gk_ = raw_ & 3;                                             \
        const unsigned short* src_ = (Base) + (size_t)row_ * K                \
                  + ((size_t)(t) << 6) + (kh) * 32 + gk_ * 8;                 \
        unsigned short* dst_ = (unsigned short*)&(larr)[r][(wave * 2 + l_) * 512]; \
        __builtin_amdgcn_global_load_lds((AS1 const void*)src_,               \
                                         (AS3 void*)dst_, 16, 0, 0);          \
    } } } while (0)

#define PHASE(rr, tt, kh, lastw) do {                                         \
    STAGEH(lA, Ab, kh, (tt) + 1, ((rr) + 2) & 3);                             \
    STAGEH(lB, Wb, kh, (tt) + 1, ((rr) + 2) & 3);                             \
    s16x8 a_[8], b_[4];                                                       \
    _Pragma("unroll") for (int mf_ = 0; mf_ < 8; ++mf_) {                     \
        const int row_ = wr * 128 + mf_ * 16 + (lane & 15);                   \
        const int raw_ = (row_ & 1) * 4 + (lane >> 4);                        \
        const int rp_ = row_ >> 1;                                            \
        a_[mf_] = *(const s16x8*)&lA[rr][rp_ * 64 + ((raw_ ^ (rp_ & 7)) << 3)]; \
    }                                                                         \
    _Pragma("unroll") for (int nf_ = 0; nf_ < 4; ++nf_) {                     \
        const int row_ = wc * 64 + nf_ * 16 + (lane & 15);                    \
        const int raw_ = (row_ & 1) * 4 + (lane >> 4);                        \
        const int rp_ = row_ >> 1;                                            \
        b_[nf_] = *(const s16x8*)&lB[rr][rp_ * 64 + ((raw_ ^ (rp_ & 7)) << 3)]; \
    }                                                                         \
    __builtin_amdgcn_s_setprio(1);                                            \
    _Pragma("unroll") for (int mf_ = 0; mf_ < 8; ++mf_)                       \
    _Pragma("unroll") for (int nf_ = 0; nf_ < 4; ++nf_)                       \
        acc[mf_][nf_] = __builtin_amdgcn_mfma_f32_16x16x32_bf16(              \
            a_[mf_], b_[nf_], acc[mf_][nf_], 0, 0, 0);                        \
    __builtin_amdgcn_s_setprio(0);                                            \
    if ((lastw)) asm volatile("s_waitcnt vmcnt(0)" ::: "memory");             \
    else         asm volatile("s_waitcnt vmcnt(4)" ::: "memory");             \
    BARRIER();                                                                \
} while (0)

__global__ __launch_bounds__(512, 2)
void gemm2p(const unsigned short* __restrict__ A, const unsigned short* __restrict__ W,
            unsigned short* __restrict__ C, int K) {
    const int cpx = gridDim.x >> 3;
    const int braw = blockIdx.x;
    const int bid = (braw & 7) * cpx + (braw >> 3);   // bijective: grid % 8 == 0
    const int mt = bid & 7;       // 2048/256 = 8 row tiles (m-inner: W-panel reuse)
    const int nt = bid >> 3;      // 0..124
    const int tid = threadIdx.x;
    const int lane = tid & 63;
    const int wave = tid >> 6;
    const int wr = wave >> 2;     // 0..1
    const int wc = wave & 3;      // 0..3

    __shared__ unsigned short lA[4][8192];   // 4 regions: 256 rows x 32 k each
    __shared__ unsigned short lB[4][8192];

    f32x4 acc[8][4];
    #pragma unroll
    for (int m = 0; m < 8; ++m)
        #pragma unroll
        for (int n = 0; n < 4; ++n)
            acc[m][n] = (f32x4){0.f, 0.f, 0.f, 0.f};

    const unsigned short* Ab = A + (size_t)(mt * 256) * K;
    const unsigned short* Wb = W + (size_t)(nt * 256) * K;
    const int nsteps = K >> 6;

    // prologue: stage tile0 k-half0 -> R0, k-half1 -> R1; R0 landed at vmcnt(4)
    STAGEH(lA, Ab, 0, 0, 0); STAGEH(lB, Wb, 0, 0, 0);
    STAGEH(lA, Ab, 1, 0, 1); STAGEH(lB, Wb, 1, 0, 1);
    asm volatile("s_waitcnt vmcnt(4)" ::: "memory");
    BARRIER();

    for (int t = 0; t < nsteps; t += 2) {       // nsteps even (32 or 64)
        PHASE(0, t, 0, false);
        PHASE(1, t, 1, false);
        PHASE(2, t + 1, 0, (t + 2 >= nsteps));
        PHASE(3, t + 1, 1, (t + 2 >= nsteps));
    }

    // epilogue: C/D layout col = lane&15, row = (lane>>4)*4 + reg
    const int colb = nt * 256 + wc * 64 + (lane & 15);
    const int rowb = mt * 256 + wr * 128 + ((lane >> 4) << 2);
    #pragma unroll
    for (int m = 0; m < 8; ++m)
        #pragma unroll
        for (int n = 0; n < 4; ++n) {
            #pragma unroll
            for (int j = 0; j < 4; ++j) {
                const size_t r = (size_t)(rowb + m * 16 + j);
                C[r * VOC + colb + n * 16] = f2bf(acc[m][n][j]);
            }
        }
}

// ---------------------------------------------------------------------------
// Fallback GEMM (fp32 operands, reg-staged convert) — used only if ws too small.
// ---------------------------------------------------------------------------
__global__ __launch_bounds__(256, 2)
void gemm_bf16(const float* __restrict__ A, const float* __restrict__ W,
               unsigned short* __restrict__ C, int K) {
    const int bid = blockIdx.x;
    const int mt = bid & 15;
    const int nt = bid >> 4;
    const int tid = threadIdx.x;
    const int lane = tid & 63;
    const int wave = tid >> 6;
    const int wm = (wave >> 1) << 6;
    const int wn = (wave & 1) << 6;

    __shared__ unsigned short lds[2][2][128 * 64];

    f32x4 acc[4][4];
    #pragma unroll
    for (int m = 0; m < 4; ++m)
        #pragma unroll
        for (int n = 0; n < 4; ++n)
            acc[m][n] = (f32x4){0.f, 0.f, 0.f, 0.f};

    const float* Ab = A + (size_t)(mt * 128) * K;
    const float* Wb = W + (size_t)(nt * 128) * K;
    const int nsteps = K >> 6;

    f32x4 ra[4][2], rb[4][2];
    int rrow[4], rk16[4];
    #pragma unroll
    for (int it = 0; it < 4; ++it) {
        int idx = it * 256 + tid;
        rrow[it] = idx >> 3;
        rk16[it] = idx & 7;
    }

    auto load_regs = [&](int step) {
        const int kb = step << 6;
        #pragma unroll
        for (int it = 0; it < 4; ++it) {
            const float* pa = Ab + (size_t)rrow[it] * K + kb + rk16[it] * 8;
            const float* pw = Wb + (size_t)rrow[it] * K + kb + rk16[it] * 8;
            ra[it][0] = *(const f32x4*)pa;
            ra[it][1] = *(const f32x4*)(pa + 4);
            rb[it][0] = *(const f32x4*)pw;
            rb[it][1] = *(const f32x4*)(pw + 4);
        }
    };

    auto write_lds = [&](int buf) {
        #pragma unroll
        for (int it = 0; it < 4; ++it) {
            const int row = rrow[it];
            const int sw = rk16[it] ^ (row & 7);
            const int off = row * 64 + sw * 8;
            u32x4 pa, pw;
            pa[0] = pk2(ra[it][0][0], ra[it][0][1]);
            pa[1] = pk2(ra[it][0][2], ra[it][0][3]);
            pa[2] = pk2(ra[it][1][0], ra[it][1][1]);
            pa[3] = pk2(ra[it][1][2], ra[it][1][3]);
            pw[0] = pk2(rb[it][0][0], rb[it][0][1]);
            pw[1] = pk2(rb[it][0][2], rb[it][0][3]);
            pw[2] = pk2(rb[it][1][0], rb[it][1][1]);
            pw[3] = pk2(rb[it][1][2], rb[it][1][3]);
            *(u32x4*)&lds[buf][0][off] = pa;
            *(u32x4*)&lds[buf][1][off] = pw;
        }
    };

    auto compute = [&](int buf) {
        #pragma unroll
        for (int ks = 0; ks < 2; ++ks) {
            const int g = ks * 4 + (lane >> 4);
            const int rsel = lane & 15;
            s16x8 afr[4], bwr[4];
            #pragma unroll
            for (int m = 0; m < 4; ++m) {
                int row = wm + m * 16 + rsel;
                afr[m] = *(const s16x8*)&lds[buf][0][row * 64 + ((g ^ (row & 7)) * 8)];
            }
            #pragma unroll
            for (int n = 0; n < 4; ++n) {
                int row = wn + n * 16 + rsel;
                bwr[n] = *(const s16x8*)&lds[buf][1][row * 64 + ((g ^ (row & 7)) * 8)];
            }
            #pragma unroll
            for (int m = 0; m < 4; ++m)
                #pragma unroll
                for (int n = 0; n < 4; ++n)
                    acc[m][n] = __builtin_amdgcn_mfma_f32_16x16x32_bf16(
                        afr[m], bwr[n], acc[m][n], 0, 0, 0);
        }
    };

    load_regs(0);
    write_lds(0);
    __syncthreads();
    for (int s = 0; s < nsteps; ++s) {
        if (s + 1 < nsteps) load_regs(s + 1);
        compute(s & 1);
        if (s + 1 < nsteps) write_lds((s + 1) & 1);
        __syncthreads();
    }

    const int colb = nt * 128 + wn + (lane & 15);
    const int rowb = mt * 128 + wm + ((lane >> 4) << 2);
    #pragma unroll
    for (int m = 0; m < 4; ++m)
        #pragma unroll
        for (int n = 0; n < 4; ++n) {
            #pragma unroll
            for (int j = 0; j < 4; ++j) {
                int r = rowb + m * 16 + j;
                int c = colb + n * 16;
                C[(size_t)r * VOC + c] = f2bf(acc[m][n][j]);
            }
        }
}

// ---------------------------------------------------------------------------
// count kernel: n_non_ignore -> 1/n (or 0), and zero d_out (graph-replay safe)
// ---------------------------------------------------------------------------
__global__ void count_kernel(const int* __restrict__ label,
                             float* __restrict__ invn, float* __restrict__ out) {
    int tid = threadIdx.x;
    int c = 0;
    for (int i = tid; i < BT; i += 256) c += (label[i] != IGN) ? 1 : 0;
    #pragma unroll
    for (int o = 32; o > 0; o >>= 1) c += __shfl_xor(c, o);
    __shared__ int red[4];
    if ((tid & 63) == 0) red[tid >> 6] = c;
    __syncthreads();
    if (tid == 0) {
        int n = red[0] + red[1] + red[2] + red[3];
        invn[0] = (n > 0) ? (1.0f / (float)n) : 0.0f;
        out[0] = 0.0f;
    }
}

// ---------------------------------------------------------------------------
// JSD kernel: one block per token, 2 passes over both bf16 logit rows.
// Pass 1: ONLINE max+sumexp per thread (rescale only on new max, ~log V times)
// -> wave combine -> block combine -> lse.  Pass 2: JSD terms -> atomicAdd.
// ---------------------------------------------------------------------------
__global__ __launch_bounds__(1024)
void jsd_kernel(const unsigned short* __restrict__ TL, const unsigned short* __restrict__ SL,
                const int* __restrict__ label, const float* __restrict__ invn,
                float* __restrict__ out) {
    const int b = blockIdx.x;
    const int tid = threadIdx.x;
    const unsigned short* tl = TL + (size_t)b * VOC;
    const unsigned short* sl = SL + (size_t)b * VOC;
    __shared__ float rmA[16], rsA[16], rmB[16], rsB[16];
    __shared__ float lse2[2];

    // pass 1: online max + sumexp for both rows
    float mp = -3.0e38f, sp = 0.f, mq = -3.0e38f, sq = 0.f;
    for (int i = tid; i < VOC / 8; i += 1024) {
        s16x8 vt = *(const s16x8*)(tl + i * 8);
        s16x8 vs = *(const s16x8*)(sl + i * 8);
        #pragma unroll
        for (int j = 0; j < 8; ++j) {
            float x = bf2f((unsigned short)vt[j]);
            if (x > mp) { sp = sp * __expf(mp - x) + 1.0f; mp = x; }
            else        { sp += __expf(x - mp); }
            float y = bf2f((unsigned short)vs[j]);
            if (y > mq) { sq = sq * __expf(mq - y) + 1.0f; mq = y; }
            else        { sq += __expf(y - mq); }
        }
    }
    #pragma unroll
    for (int o = 32; o > 0; o >>= 1) {
        float om = __shfl_xor(mp, o), os = __shfl_xor(sp, o);
        float nm = fmaxf(mp, om);
        sp = sp * __expf(mp - nm) + os * __expf(om - nm);
        mp = nm;
        om = __shfl_xor(mq, o); os = __shfl_xor(sq, o);
        nm = fmaxf(mq, om);
        sq = sq * __expf(mq - nm) + os * __expf(om - nm);
        mq = nm;
    }
    if ((tid & 63) == 0) {
        rmA[tid >> 6] = mp; rsA[tid >> 6] = sp;
        rmB[tid >> 6] = mq; rsB[tid >> 6] = sq;
    }
    __syncthreads();
    if (tid == 0) {
        float m1 = rmA[0], s1 = 0.f, m2 = rmB[0], s2 = 0.f;
        for (int w = 1; w < 16; ++w) { m1 = fmaxf(m1, rmA[w]); m2 = fmaxf(m2, rmB[w]); }
        for (int w = 0; w < 16; ++w) {
            s1 += rsA[w] * __expf(rmA[w] - m1);
            s2 += rsB[w] * __expf(rmB[w] - m2);
        }
        lse2[0] = m1 + __logf(s1);
        lse2[1] = m2 + __logf(s2);
    }
    __syncthreads();
    const float lsep = lse2[0];
    const float lseq = lse2[1];

    // pass 2: JSD
    float accj = 0.f;
    for (int i = tid; i < VOC / 8; i += 1024) {
        s16x8 vt = *(const s16x8*)(tl + i * 8);
        s16x8 vs = *(const s16x8*)(sl + i * 8);
        #pragma unroll
        for (int j = 0; j < 8; ++j) {
            float lp = bf2f((unsigned short)vt[j]) - lsep;   // teacher log-prob
            float lq = bf2f((unsigned short)vs[j]) - lseq;   // student log-prob
            float m0 = fmaxf(lp, lq);
            float e = __expf(-fabsf(lp - lq));
            float lm = m0 + __logf(0.5f * (1.0f + e));
            accj += 0.5f * (__expf(lp) * (lp - lm) + __expf(lq) * (lq - lm));
        }
    }
    #pragma unroll
    for (int o = 32; o > 0; o >>= 1) accj += __shfl_xor(accj, o);
    if ((tid & 63) == 0) rmA[tid >> 6] = accj;
    __syncthreads();
    if (tid == 0) {
        float a = 0.f;
        for (int w = 0; w < 16; ++w) a += rmA[w];
        if (label[b] != IGN) atomicAdd(out, a * invn[0]);
    }
}

extern "C" void kernel_launch(void* const* d_in, const int* in_sizes, int n_in,
                              void* d_out, int out_size, void* d_ws, size_t ws_size,
                              hipStream_t stream) {
    const float* s_in = (const float*)d_in[0];   // [BT, 2048]
    const float* t_in = (const float*)d_in[1];   // [BT, 4096]
    const float* Ws   = (const float*)d_in[2];   // [VOC, 2048]
    const float* Wt   = (const float*)d_in[3];   // [VOC, 4096]
    const int* label  = (const int*)d_in[4];     // [BT]
    float* out = (float*)d_out;

    const size_t L   = (size_t)BT * VOC;
    const size_t eWt = (size_t)VOC * 4096;
    const size_t eWs = (size_t)VOC * 2048;
    const size_t eAt = (size_t)BT * 4096;
    const size_t eAs = (size_t)BT * 2048;

    const size_t need_full = (2 * L + eWt + eWs + eAt + eAs) * sizeof(unsigned short) + 64;
    const size_t need_min  = 2 * L * sizeof(unsigned short) + 64;

    if (ws_size >= need_full) {
        unsigned short* logT = (unsigned short*)d_ws;
        unsigned short* logS = logT + L;
        unsigned short* Wtb  = logS + L;
        unsigned short* Wsb  = Wtb + eWt;
        unsigned short* Atb  = Wsb + eWs;
        unsigned short* Asb  = Atb + eAt;
        float* invn = (float*)(Asb + eAs);

        cvt_kernel<<<dim3(2048), dim3(256), 0, stream>>>(Wt, Wtb, (int)(eWt / 8));
        cvt_kernel<<<dim3(2048), dim3(256), 0, stream>>>(Ws, Wsb, (int)(eWs / 8));
        cvt_kernel<<<dim3(1024), dim3(256), 0, stream>>>(t_in, Atb, (int)(eAt / 8));
        cvt_kernel<<<dim3(1024), dim3(256), 0, stream>>>(s_in, Asb, (int)(eAs / 8));
        count_kernel<<<dim3(1), dim3(256), 0, stream>>>(label, invn, out);
        gemm2p<<<dim3(8 * (VOC / 256)), dim3(512), 0, stream>>>(Atb, Wtb, logT, 4096);
        gemm2p<<<dim3(8 * (VOC / 256)), dim3(512), 0, stream>>>(Asb, Wsb, logS, 2048);
        jsd_kernel<<<dim3(BT), dim3(1024), 0, stream>>>(logT, logS, label, invn, out);
    } else {
        if (ws_size < need_min) return;
        unsigned short* logT = (unsigned short*)d_ws;
        unsigned short* logS = logT + L;
        float* invn = (float*)(logS + L);

        count_kernel<<<dim3(1), dim3(256), 0, stream>>>(label, invn, out);
        gemm_bf16<<<dim3(16 * (VOC / 128)), dim3(256), 0, stream>>>(t_in, Wt, logT, 4096);
        gemm_bf16<<<dim3(16 * (VOC / 128)), dim3(256), 0, stream>>>(s_in, Ws, logS, 2048);
        jsd_kernel<<<dim3(BT), dim3(1024), 0, stream>>>(logT, logS, label, invn, out);
    }
}

// Round 6
// 1100.147 us; speedup vs baseline: 1.1616x; 1.1616x over previous
//
#include <hip/hip_runtime.h>
#include <hip/hip_bf16.h>

#define BT 2048
#define VOC 32000
#define IGN (-100)

typedef __attribute__((ext_vector_type(4))) float f32x4;
typedef __attribute__((ext_vector_type(8))) short s16x8;
typedef __attribute__((ext_vector_type(4))) unsigned int u32x4;

#define AS1 __attribute__((address_space(1)))
#define AS3 __attribute__((address_space(3)))

__device__ __forceinline__ unsigned short f2bf(float f) {
    union { __hip_bfloat16 h; unsigned short u; } c;
    c.h = __float2bfloat16(f);
    return c.u;
}
__device__ __forceinline__ float bf2f(unsigned short u) {
    union { unsigned int u; float f; } c;
    c.u = ((unsigned int)u) << 16;
    return c.f;
}
__device__ __forceinline__ unsigned int pk2(float a, float b) {
    return (unsigned int)f2bf(a) | ((unsigned int)f2bf(b) << 16);
}

// ---------------------------------------------------------------------------
// fp32 -> bf16 pre-convert (memory-bound)
// ---------------------------------------------------------------------------
__global__ __launch_bounds__(256)
void cvt_kernel(const float* __restrict__ in, unsigned short* __restrict__ out, int n8) {
    for (int i = blockIdx.x * 256 + threadIdx.x; i < n8; i += gridDim.x * 256) {
        f32x4 a = ((const f32x4*)in)[2 * i];
        f32x4 b = ((const f32x4*)in)[2 * i + 1];
        u32x4 o;
        o[0] = pk2(a[0], a[1]);
        o[1] = pk2(a[2], a[3]);
        o[2] = pk2(b[0], b[1]);
        o[3] = pk2(b[2], b[3]);
        ((u32x4*)out)[i] = o;
    }
}

// ---------------------------------------------------------------------------
// 256x256 GEMM (bf16 operands), 4-region K-half ring, 1 barrier per phase.
// C[m,v] = sum_k A[m,k] * W[v,k].  BK=64 = 2 K-halves (one 16x16x32 step each).
// 512 thr (8 waves 2Mx4N), per-wave 128x64 out.
//
// EXACT round-4 structure (proven 44% MfmaUtil) with ONE change: pipeline
// depth 1 -> 2 phases.  Phase p consumes region p%4 and stages region
// (p+3)%4 (= the region consumed in phase p-1; dead after p-1's barrier,
// so WAR-safe).  End-of-phase wait is vmcnt(8): leaves the 8 gloads of
// phases p and p-1 in flight; FIFO vmcnt semantics guarantee region p+1
// (issued in phase p-2, 3 phases before its use) has fully landed.
// Tail counts: kh0: 8/0;  kh1: 8/4/0 (derived from remaining stage counts).
// Prologue stages 3 regions (phases 0,1,2), vmcnt(8) -> region 0 ready.
// ---------------------------------------------------------------------------
#define FENCE() asm volatile("" ::: "memory")
#define BARRIER() do { FENCE(); __builtin_amdgcn_s_barrier(); FENCE(); } while (0)
#define WAIT_LGKM0() do { asm volatile("s_waitcnt lgkmcnt(0)" ::: "memory"); \
                          __builtin_amdgcn_sched_barrier(0); } while (0)

#define STAGEH(larr, Base, kh, t, r) do { if ((t) < nsteps) {                 \
    _Pragma("unroll")                                                         \
    for (int l_ = 0; l_ < 2; ++l_) {                                          \
        const int gi_ = (wave * 2 + l_) * 64 + lane;                          \
        const int rp_ = gi_ >> 3, sgi_ = gi_ & 7;                             \
        const int raw_ = sgi_ ^ (rp_ & 7);                                    \
        const int row_ = rp_ * 2 + (raw_ >> 2);                               \
        const int gk_ = raw_ & 3;                                             \
        const unsigned short* src_ = (Base) + (size_t)row_ * K                \
                  + ((size_t)(t) << 6) + (kh) * 32 + gk_ * 8;                 \
        unsigned short* dst_ = (unsigned short*)&(larr)[r][(wave * 2 + l_) * 512]; \
        __builtin_amdgcn_global_load_lds((AS1 const void*)src_,               \
                                         (AS3 void*)dst_, 16, 0, 0);          \
    } } } while (0)

__global__ __launch_bounds__(512, 2)
void gemm2p(const unsigned short* __restrict__ A, const unsigned short* __restrict__ W,
            unsigned short* __restrict__ C, int K) {
    const int cpx = gridDim.x >> 3;
    const int braw = blockIdx.x;
    const int bid = (braw & 7) * cpx + (braw >> 3);   // bijective: grid % 8 == 0
    const int mt = bid & 7;       // 2048/256 = 8 row tiles (m-inner: W-panel reuse)
    const int nt = bid >> 3;      // 0..124
    const int tid = threadIdx.x;
    const int lane = tid & 63;
    const int wave = tid >> 6;
    const int wr = wave >> 2;     // 0..1
    const int wc = wave & 3;      // 0..3

    __shared__ unsigned short lA[4][8192];   // 4 regions: 256 rows x 32 k each
    __shared__ unsigned short lB[4][8192];

    f32x4 acc[8][4];
    #pragma unroll
    for (int m = 0; m < 8; ++m)
        #pragma unroll
        for (int n = 0; n < 4; ++n)
            acc[m][n] = (f32x4){0.f, 0.f, 0.f, 0.f};

    const unsigned short* Ab = A + (size_t)(mt * 256) * K;
    const unsigned short* Wb = W + (size_t)(nt * 256) * K;
    const int nsteps = K >> 6;

    // prologue: stage regions for phases 0,1,2; vmcnt(8) -> region 0 landed
    STAGEH(lA, Ab, 0, 0, 0); STAGEH(lB, Wb, 0, 0, 0);
    STAGEH(lA, Ab, 1, 0, 1); STAGEH(lB, Wb, 1, 0, 1);
    STAGEH(lA, Ab, 0, 1, 2); STAGEH(lB, Wb, 0, 1, 2);
    asm volatile("s_waitcnt vmcnt(8)" ::: "memory");
    BARRIER();

    for (int t = 0; t < nsteps; ++t) {
        #pragma unroll
        for (int kh = 0; kh < 2; ++kh) {
            const int r = ((t & 1) << 1) | kh;
            // ds-read this phase's fragments (one k-step) from region r
            s16x8 a[8], b[4];
            #pragma unroll
            for (int mf = 0; mf < 8; ++mf) {
                const int row = wr * 128 + mf * 16 + (lane & 15);
                const int raw = (row & 1) * 4 + (lane >> 4);
                const int rp = row >> 1;
                a[mf] = *(const s16x8*)&lA[r][rp * 64 + ((raw ^ (rp & 7)) << 3)];
            }
            #pragma unroll
            for (int nf = 0; nf < 4; ++nf) {
                const int row = wc * 64 + nf * 16 + (lane & 15);
                const int raw = (row & 1) * 4 + (lane >> 4);
                const int rp = row >> 1;
                b[nf] = *(const s16x8*)&lB[r][rp * 64 + ((raw ^ (rp & 7)) << 3)];
            }
            // stage phase p+3's data into region (r+3)&3 (consumed in p-1; dead)
            {
                const int st = t + 1 + kh;      // kh0 -> (t+1, kh1); kh1 -> (t+2, kh0)
                const int skh = 1 - kh;
                const int sr = (r + 3) & 3;
                STAGEH(lA, Ab, skh, st, sr);
                STAGEH(lB, Wb, skh, st, sr);
            }
            // own-reads done -> MFMA burst (waves drift; LDS/MFMA overlap)
            WAIT_LGKM0();
            __builtin_amdgcn_s_setprio(1);
            #pragma unroll
            for (int mf = 0; mf < 8; ++mf)
                #pragma unroll
                for (int nf = 0; nf < 4; ++nf)
                    acc[mf][nf] = __builtin_amdgcn_mfma_f32_16x16x32_bf16(
                        a[mf], b[nf], acc[mf][nf], 0, 0, 0);
            __builtin_amdgcn_s_setprio(0);
            // ensure next phase's region landed; keep <=2 phases of gloads in flight
            if (kh == 0) {
                if (t + 1 < nsteps) asm volatile("s_waitcnt vmcnt(8)" ::: "memory");
                else                asm volatile("s_waitcnt vmcnt(0)" ::: "memory");
            } else {
                if (t + 2 < nsteps)      asm volatile("s_waitcnt vmcnt(8)" ::: "memory");
                else if (t + 1 < nsteps) asm volatile("s_waitcnt vmcnt(4)" ::: "memory");
                else                     asm volatile("s_waitcnt vmcnt(0)" ::: "memory");
            }
            BARRIER();
        }
    }

    // epilogue: C/D layout col = lane&15, row = (lane>>4)*4 + reg
    const int colb = nt * 256 + wc * 64 + (lane & 15);
    const int rowb = mt * 256 + wr * 128 + ((lane >> 4) << 2);
    #pragma unroll
    for (int m = 0; m < 8; ++m)
        #pragma unroll
        for (int n = 0; n < 4; ++n) {
            #pragma unroll
            for (int j = 0; j < 4; ++j) {
                const size_t r = (size_t)(rowb + m * 16 + j);
                C[r * VOC + colb + n * 16] = f2bf(acc[m][n][j]);
            }
        }
}

// ---------------------------------------------------------------------------
// Fallback GEMM (fp32 operands, reg-staged convert) — used only if ws too small.
// ---------------------------------------------------------------------------
__global__ __launch_bounds__(256, 2)
void gemm_bf16(const float* __restrict__ A, const float* __restrict__ W,
               unsigned short* __restrict__ C, int K) {
    const int bid = blockIdx.x;
    const int mt = bid & 15;
    const int nt = bid >> 4;
    const int tid = threadIdx.x;
    const int lane = tid & 63;
    const int wave = tid >> 6;
    const int wm = (wave >> 1) << 6;
    const int wn = (wave & 1) << 6;

    __shared__ unsigned short lds[2][2][128 * 64];

    f32x4 acc[4][4];
    #pragma unroll
    for (int m = 0; m < 4; ++m)
        #pragma unroll
        for (int n = 0; n < 4; ++n)
            acc[m][n] = (f32x4){0.f, 0.f, 0.f, 0.f};

    const float* Ab = A + (size_t)(mt * 128) * K;
    const float* Wb = W + (size_t)(nt * 128) * K;
    const int nsteps = K >> 6;

    f32x4 ra[4][2], rb[4][2];
    int rrow[4], rk16[4];
    #pragma unroll
    for (int it = 0; it < 4; ++it) {
        int idx = it * 256 + tid;
        rrow[it] = idx >> 3;
        rk16[it] = idx & 7;
    }

    auto load_regs = [&](int step) {
        const int kb = step << 6;
        #pragma unroll
        for (int it = 0; it < 4; ++it) {
            const float* pa = Ab + (size_t)rrow[it] * K + kb + rk16[it] * 8;
            const float* pw = Wb + (size_t)rrow[it] * K + kb + rk16[it] * 8;
            ra[it][0] = *(const f32x4*)pa;
            ra[it][1] = *(const f32x4*)(pa + 4);
            rb[it][0] = *(const f32x4*)pw;
            rb[it][1] = *(const f32x4*)(pw + 4);
        }
    };

    auto write_lds = [&](int buf) {
        #pragma unroll
        for (int it = 0; it < 4; ++it) {
            const int row = rrow[it];
            const int sw = rk16[it] ^ (row & 7);
            const int off = row * 64 + sw * 8;
            u32x4 pa, pw;
            pa[0] = pk2(ra[it][0][0], ra[it][0][1]);
            pa[1] = pk2(ra[it][0][2], ra[it][0][3]);
            pa[2] = pk2(ra[it][1][0], ra[it][1][1]);
            pa[3] = pk2(ra[it][1][2], ra[it][1][3]);
            pw[0] = pk2(rb[it][0][0], rb[it][0][1]);
            pw[1] = pk2(rb[it][0][2], rb[it][0][3]);
            pw[2] = pk2(rb[it][1][0], rb[it][1][1]);
            pw[3] = pk2(rb[it][1][2], rb[it][1][3]);
            *(u32x4*)&lds[buf][0][off] = pa;
            *(u32x4*)&lds[buf][1][off] = pw;
        }
    };

    auto compute = [&](int buf) {
        #pragma unroll
        for (int ks = 0; ks < 2; ++ks) {
            const int g = ks * 4 + (lane >> 4);
            const int rsel = lane & 15;
            s16x8 afr[4], bwr[4];
            #pragma unroll
            for (int m = 0; m < 4; ++m) {
                int row = wm + m * 16 + rsel;
                afr[m] = *(const s16x8*)&lds[buf][0][row * 64 + ((g ^ (row & 7)) * 8)];
            }
            #pragma unroll
            for (int n = 0; n < 4; ++n) {
                int row = wn + n * 16 + rsel;
                bwr[n] = *(const s16x8*)&lds[buf][1][row * 64 + ((g ^ (row & 7)) * 8)];
            }
            #pragma unroll
            for (int m = 0; m < 4; ++m)
                #pragma unroll
                for (int n = 0; n < 4; ++n)
                    acc[m][n] = __builtin_amdgcn_mfma_f32_16x16x32_bf16(
                        afr[m], bwr[n], acc[m][n], 0, 0, 0);
        }
    };

    load_regs(0);
    write_lds(0);
    __syncthreads();
    for (int s = 0; s < nsteps; ++s) {
        if (s + 1 < nsteps) load_regs(s + 1);
        compute(s & 1);
        if (s + 1 < nsteps) write_lds((s + 1) & 1);
        __syncthreads();
    }

    const int colb = nt * 128 + wn + (lane & 15);
    const int rowb = mt * 128 + wm + ((lane >> 4) << 2);
    #pragma unroll
    for (int m = 0; m < 4; ++m)
        #pragma unroll
        for (int n = 0; n < 4; ++n) {
            #pragma unroll
            for (int j = 0; j < 4; ++j) {
                int r = rowb + m * 16 + j;
                int c = colb + n * 16;
                C[(size_t)r * VOC + c] = f2bf(acc[m][n][j]);
            }
        }
}

// ---------------------------------------------------------------------------
// count kernel: n_non_ignore -> 1/n (or 0), and zero d_out (graph-replay safe)
// ---------------------------------------------------------------------------
__global__ void count_kernel(const int* __restrict__ label,
                             float* __restrict__ invn, float* __restrict__ out) {
    int tid = threadIdx.x;
    int c = 0;
    for (int i = tid; i < BT; i += 256) c += (label[i] != IGN) ? 1 : 0;
    #pragma unroll
    for (int o = 32; o > 0; o >>= 1) c += __shfl_xor(c, o);
    __shared__ int red[4];
    if ((tid & 63) == 0) red[tid >> 6] = c;
    __syncthreads();
    if (tid == 0) {
        int n = red[0] + red[1] + red[2] + red[3];
        invn[0] = (n > 0) ? (1.0f / (float)n) : 0.0f;
        out[0] = 0.0f;
    }
}

// ---------------------------------------------------------------------------
// JSD kernel: one block per token, 2 passes over both bf16 logit rows.
// Pass 1: ONLINE max+sumexp per thread (rescale only on new max, ~log V times)
// -> wave combine -> block combine -> lse.  Pass 2: JSD terms -> atomicAdd.
// ---------------------------------------------------------------------------
__global__ __launch_bounds__(1024)
void jsd_kernel(const unsigned short* __restrict__ TL, const unsigned short* __restrict__ SL,
                const int* __restrict__ label, const float* __restrict__ invn,
                float* __restrict__ out) {
    const int b = blockIdx.x;
    const int tid = threadIdx.x;
    const unsigned short* tl = TL + (size_t)b * VOC;
    const unsigned short* sl = SL + (size_t)b * VOC;
    __shared__ float rmA[16], rsA[16], rmB[16], rsB[16];
    __shared__ float lse2[2];

    // pass 1: online max + sumexp for both rows
    float mp = -3.0e38f, sp = 0.f, mq = -3.0e38f, sq = 0.f;
    for (int i = tid; i < VOC / 8; i += 1024) {
        s16x8 vt = *(const s16x8*)(tl + i * 8);
        s16x8 vs = *(const s16x8*)(sl + i * 8);
        #pragma unroll
        for (int j = 0; j < 8; ++j) {
            float x = bf2f((unsigned short)vt[j]);
            if (x > mp) { sp = sp * __expf(mp - x) + 1.0f; mp = x; }
            else        { sp += __expf(x - mp); }
            float y = bf2f((unsigned short)vs[j]);
            if (y > mq) { sq = sq * __expf(mq - y) + 1.0f; mq = y; }
            else        { sq += __expf(y - mq); }
        }
    }
    #pragma unroll
    for (int o = 32; o > 0; o >>= 1) {
        float om = __shfl_xor(mp, o), os = __shfl_xor(sp, o);
        float nm = fmaxf(mp, om);
        sp = sp * __expf(mp - nm) + os * __expf(om - nm);
        mp = nm;
        om = __shfl_xor(mq, o); os = __shfl_xor(sq, o);
        nm = fmaxf(mq, om);
        sq = sq * __expf(mq - nm) + os * __expf(om - nm);
        mq = nm;
    }
    if ((tid & 63) == 0) {
        rmA[tid >> 6] = mp; rsA[tid >> 6] = sp;
        rmB[tid >> 6] = mq; rsB[tid >> 6] = sq;
    }
    __syncthreads();
    if (tid == 0) {
        float m1 = rmA[0], s1 = 0.f, m2 = rmB[0], s2 = 0.f;
        for (int w = 1; w < 16; ++w) { m1 = fmaxf(m1, rmA[w]); m2 = fmaxf(m2, rmB[w]); }
        for (int w = 0; w < 16; ++w) {
            s1 += rsA[w] * __expf(rmA[w] - m1);
            s2 += rsB[w] * __expf(rmB[w] - m2);
        }
        lse2[0] = m1 + __logf(s1);
        lse2[1] = m2 + __logf(s2);
    }
    __syncthreads();
    const float lsep = lse2[0];
    const float lseq = lse2[1];

    // pass 2: JSD
    float accj = 0.f;
    for (int i = tid; i < VOC / 8; i += 1024) {
        s16x8 vt = *(const s16x8*)(tl + i * 8);
        s16x8 vs = *(const s16x8*)(sl + i * 8);
        #pragma unroll
        for (int j = 0; j < 8; ++j) {
            float lp = bf2f((unsigned short)vt[j]) - lsep;   // teacher log-prob
            float lq = bf2f((unsigned short)vs[j]) - lseq;   // student log-prob
            float m0 = fmaxf(lp, lq);
            float e = __expf(-fabsf(lp - lq));
            float lm = m0 + __logf(0.5f * (1.0f + e));
            accj += 0.5f * (__expf(lp) * (lp - lm) + __expf(lq) * (lq - lm));
        }
    }
    #pragma unroll
    for (int o = 32; o > 0; o >>= 1) accj += __shfl_xor(accj, o);
    if ((tid & 63) == 0) rmA[tid >> 6] = accj;
    __syncthreads();
    if (tid == 0) {
        float a = 0.f;
        for (int w = 0; w < 16; ++w) a += rmA[w];
        if (label[b] != IGN) atomicAdd(out, a * invn[0]);
    }
}

extern "C" void kernel_launch(void* const* d_in, const int* in_sizes, int n_in,
                              void* d_out, int out_size, void* d_ws, size_t ws_size,
                              hipStream_t stream) {
    const float* s_in = (const float*)d_in[0];   // [BT, 2048]
    const float* t_in = (const float*)d_in[1];   // [BT, 4096]
    const float* Ws   = (const float*)d_in[2];   // [VOC, 2048]
    const float* Wt   = (const float*)d_in[3];   // [VOC, 4096]
    const int* label  = (const int*)d_in[4];     // [BT]
    float* out = (float*)d_out;

    const size_t L   = (size_t)BT * VOC;
    const size_t eWt = (size_t)VOC * 4096;
    const size_t eWs = (size_t)VOC * 2048;
    const size_t eAt = (size_t)BT * 4096;
    const size_t eAs = (size_t)BT * 2048;

    const size_t need_full = (2 * L + eWt + eWs + eAt + eAs) * sizeof(unsigned short) + 64;
    const size_t need_min  = 2 * L * sizeof(unsigned short) + 64;

    if (ws_size >= need_full) {
        unsigned short* logT = (unsigned short*)d_ws;
        unsigned short* logS = logT + L;
        unsigned short* Wtb  = logS + L;
        unsigned short* Wsb  = Wtb + eWt;
        unsigned short* Atb  = Wsb + eWs;
        unsigned short* Asb  = Atb + eAt;
        float* invn = (float*)(Asb + eAs);

        cvt_kernel<<<dim3(2048), dim3(256), 0, stream>>>(Wt, Wtb, (int)(eWt / 8));
        cvt_kernel<<<dim3(2048), dim3(256), 0, stream>>>(Ws, Wsb, (int)(eWs / 8));
        cvt_kernel<<<dim3(1024), dim3(256), 0, stream>>>(t_in, Atb, (int)(eAt / 8));
        cvt_kernel<<<dim3(1024), dim3(256), 0, stream>>>(s_in, Asb, (int)(eAs / 8));
        count_kernel<<<dim3(1), dim3(256), 0, stream>>>(label, invn, out);
        gemm2p<<<dim3(8 * (VOC / 256)), dim3(512), 0, stream>>>(Atb, Wtb, logT, 4096);
        gemm2p<<<dim3(8 * (VOC / 256)), dim3(512), 0, stream>>>(Asb, Wsb, logS, 2048);
        jsd_kernel<<<dim3(BT), dim3(1024), 0, stream>>>(logT, logS, label, invn, out);
    } else {
        if (ws_size < need_min) return;
        unsigned short* logT = (unsigned short*)d_ws;
        unsigned short* logS = logT + L;
        float* invn = (float*)(logS + L);

        count_kernel<<<dim3(1), dim3(256), 0, stream>>>(label, invn, out);
        gemm_bf16<<<dim3(16 * (VOC / 128)), dim3(256), 0, stream>>>(t_in, Wt, logT, 4096);
        gemm_bf16<<<dim3(16 * (VOC / 128)), dim3(256), 0, stream>>>(s_in, Ws, logS, 2048);
        jsd_kernel<<<dim3(BT), dim3(1024), 0, stream>>>(logT, logS, label, invn, out);
    }
}